// Round 13
// baseline (421.274 us; speedup 1.0000x reference)
//
#include <hip/hip_runtime.h>

constexpr int N_SRC = 100000;
constexpr int N_DST = 100000;
constexpr int E     = 1600000;
constexpr int D     = 64;
constexpr float LN_EPS = 1e-5f;

constexpr int BROWS  = 128;            // dst rows per bucket
constexpr int NBK    = (N_DST + BROWS - 1) / BROWS;   // 782 buckets
constexpr int NCHUNK = NBK;            // edge chunks == grid of k_sort
constexpr int CHUNKB = E / NCHUNK;     // 2046 (last chunk takes +28)
constexpr int MAXB   = 4096;           // per-bucket edge cap (mean 2046)
constexpr int FB     = 72;             // padded k-stride (ushorts) for weight LDS
constexpr int ZROW   = N_SRC;          // zeroed dummy msg row for tail lanes

typedef __attribute__((ext_vector_type(8))) short bf16x8;
typedef __attribute__((ext_vector_type(4))) float f32x4;

__device__ inline unsigned short bfh(float x) {
    union { float f; unsigned u; } c; c.f = x; return (unsigned short)(c.u >> 16);  // truncate
}
__device__ inline float bff(unsigned short b) {
    union { unsigned u; float f; } c; c.u = (unsigned)b << 16; return c.f;
}
__device__ inline float asf(unsigned u) {
    union { unsigned u; float f; } c; c.u = u; return c.f;
}
__device__ inline unsigned short bfrne(float x) {
    union { float f; unsigned u; } c; c.f = x;
    unsigned u = c.u + (0x7FFFu + ((c.u >> 16) & 1u));
    return (unsigned short)(u >> 16);
}

// ---------------------------------------------------------------------------
// k_film: block = 128 rows (4 waves x 2 M-tiles). Weights split hi/lo once per
// block into padded LDS (coalesced staging). 6 ds_read_b128 + 18 MFMA per
// (t,ks); 3-term split ~ f32 accuracy. bf16-RNE output. Block 0 additionally
// zeroes the ZROW dummy row and the k_sort grid-barrier counters.
// ---------------------------------------------------------------------------
__global__ __launch_bounds__(256) void k_film(const float* __restrict__ feat,
                                              const float* __restrict__ Ww,   // [64][64]
                                              const float* __restrict__ Fw,   // [64][128]
                                              unsigned short* __restrict__ msgb,
                                              int* __restrict__ ctr) {
    __shared__ unsigned short wl[6 * 64 * FB];   // 55296 B

    const int tid  = threadIdx.x;
    const int lane = tid & 63;
    const int wid  = tid >> 6;
    const int m    = lane & 15;
    const int kg   = lane >> 4;
    const int mrow0 = (blockIdx.x * 4 + wid) * 32;   // 32 rows per wave

    if (blockIdx.x == 0) {
        if (tid < 64) msgb[(size_t)ZROW * 64 + tid] = 0;     // zero dummy row
        if (tid >= 64 && tid < 67)                           // zero barrier ctrs
            __hip_atomic_store(&ctr[tid - 64], 0, __ATOMIC_RELAXED,
                               __HIP_MEMORY_SCOPE_AGENT);
    }

    // ---- A fragments: 2 mtiles x 2 ksteps, hi/lo (registers) ----
    bf16x8 ahi[2][2], alo[2][2];
#pragma unroll
    for (int mt = 0; mt < 2; ++mt) {
        const int rbase = mrow0 + mt * 16 + m;
        const int r = (rbase < N_SRC) ? rbase : 0;
#pragma unroll
        for (int ks = 0; ks < 2; ++ks) {
            const float* p = feat + (size_t)r * 64 + ks * 32 + kg * 8;
            const float4 x0 = *reinterpret_cast<const float4*>(p);
            const float4 x1 = *reinterpret_cast<const float4*>(p + 4);
            const float a[8] = {x0.x, x0.y, x0.z, x0.w, x1.x, x1.y, x1.z, x1.w};
            bf16x8 h, l;
#pragma unroll
            for (int j = 0; j < 8; ++j) {
                const unsigned short hb = bfh(a[j]);
                h[j] = (short)hb;
                l[j] = (short)bfh(a[j] - bff(hb));
            }
            ahi[mt][ks] = h; alo[mt][ks] = l;
        }
    }

    // ---- weight split -> LDS, once per block (coalesced: n = task & 63) ----
    for (int task = tid; task < 1536; task += 256) {
        const int n  = task & 63;
        const int g  = (task >> 6) & 7;
        const int mu = task >> 9;                 // 0=Wm, 1=gamma, 2=beta
        const float* src;
        int stride;
        if (mu == 0)      { src = Ww + n;       stride = 64;  }
        else if (mu == 1) { src = Fw + n;       stride = 128; }
        else              { src = Fw + 64 + n;  stride = 128; }
        bf16x8 h, l;
#pragma unroll
        for (int j = 0; j < 8; ++j) {
            const float v = src[(size_t)(8 * g + j) * stride];
            const unsigned short hb = bfh(v);
            h[j] = (short)hb;
            l[j] = (short)bfh(v - bff(hb));
        }
        *reinterpret_cast<bf16x8*>(&wl[(2 * mu + 0) * 64 * FB + n * FB + g * 8]) = h;
        *reinterpret_cast<bf16x8*>(&wl[(2 * mu + 1) * 64 * FB + n * FB + g * 8]) = l;
    }
    __syncthreads();

    const f32x4 zero = {0.f, 0.f, 0.f, 0.f};

#pragma unroll
    for (int t = 0; t < 4; ++t) {
        f32x4 am[2], ag[2], ab[2];
#pragma unroll
        for (int i = 0; i < 2; ++i) { am[i] = zero; ag[i] = zero; ab[i] = zero; }

#pragma unroll
        for (int ks = 0; ks < 2; ++ks) {
            const int n = t * 16 + m;
            const int base = n * FB + ks * 32 + kg * 8;
            const bf16x8 wmh = *reinterpret_cast<const bf16x8*>(&wl[0 * 64 * FB + base]);
            const bf16x8 wml = *reinterpret_cast<const bf16x8*>(&wl[1 * 64 * FB + base]);
            const bf16x8 wgh = *reinterpret_cast<const bf16x8*>(&wl[2 * 64 * FB + base]);
            const bf16x8 wgl = *reinterpret_cast<const bf16x8*>(&wl[3 * 64 * FB + base]);
            const bf16x8 wbh = *reinterpret_cast<const bf16x8*>(&wl[4 * 64 * FB + base]);
            const bf16x8 wbl = *reinterpret_cast<const bf16x8*>(&wl[5 * 64 * FB + base]);
#pragma unroll
            for (int mt = 0; mt < 2; ++mt) {
                am[mt] = __builtin_amdgcn_mfma_f32_16x16x32_bf16(ahi[mt][ks], wmh, am[mt], 0, 0, 0);
                am[mt] = __builtin_amdgcn_mfma_f32_16x16x32_bf16(ahi[mt][ks], wml, am[mt], 0, 0, 0);
                am[mt] = __builtin_amdgcn_mfma_f32_16x16x32_bf16(alo[mt][ks], wmh, am[mt], 0, 0, 0);
                ag[mt] = __builtin_amdgcn_mfma_f32_16x16x32_bf16(ahi[mt][ks], wgh, ag[mt], 0, 0, 0);
                ag[mt] = __builtin_amdgcn_mfma_f32_16x16x32_bf16(ahi[mt][ks], wgl, ag[mt], 0, 0, 0);
                ag[mt] = __builtin_amdgcn_mfma_f32_16x16x32_bf16(alo[mt][ks], wgh, ag[mt], 0, 0, 0);
                ab[mt] = __builtin_amdgcn_mfma_f32_16x16x32_bf16(ahi[mt][ks], wbh, ab[mt], 0, 0, 0);
                ab[mt] = __builtin_amdgcn_mfma_f32_16x16x32_bf16(ahi[mt][ks], wbl, ab[mt], 0, 0, 0);
                ab[mt] = __builtin_amdgcn_mfma_f32_16x16x32_bf16(alo[mt][ks], wbh, ab[mt], 0, 0, 0);
            }
        }

#pragma unroll
        for (int mt = 0; mt < 2; ++mt) {
            const int rb = mrow0 + mt * 16;
            if (rb < N_SRC) {      // N_SRC % 16 == 0: mtile all-or-nothing
#pragma unroll
                for (int r4 = 0; r4 < 4; ++r4) {
                    const int row = rb + kg * 4 + r4;
                    const float o = fmaxf(ag[mt][r4] * am[mt][r4] + ab[mt][r4], 0.f);
                    msgb[(size_t)row * 64 + t * 16 + m] = bfrne(o);
                }
            }
        }
    }
}

// ---------------------------------------------------------------------------
// grid barrier: single-use counter per barrier; counters pre-zeroed by k_film.
// ---------------------------------------------------------------------------
__device__ inline void gbar(int* ctr, int nblk) {
    __syncthreads();
    if (threadIdx.x == 0) {
        __threadfence();                      // release prior global writes
        atomicAdd(ctr, 1);
        while (atomicAdd(ctr, 0) < nblk) { __builtin_amdgcn_s_sleep(4); }
        __threadfence();                      // acquire
    }
    __syncthreads();
}

// ---------------------------------------------------------------------------
// k_sort: hist + per-bucket chunk-scan + bucket-offset scan + scatter, fused
// via grid barriers. 782 blocks x 256 threads (all co-resident: 8 blk/CU cap).
// All data atomics in LDS; barrier atomics are 3 global ints total.
// ---------------------------------------------------------------------------
__global__ __launch_bounds__(256) void k_sort(const int* __restrict__ esrc,
                                              const int* __restrict__ edst,
                                              int* __restrict__ H,       // [NBK][NCHUNK]
                                              int* __restrict__ bstart,  // [NBK+1]
                                              unsigned* __restrict__ pairs,
                                              int* __restrict__ ctr) {
    __shared__ int sh[NBK];
    const int tid  = threadIdx.x;
    const int lane = tid & 63;
    const int wid  = tid >> 6;
    const int c    = blockIdx.x;          // chunk id (phases A,D), bucket id (B)
    const int e0   = c * CHUNKB;
    const int e1   = (c == NCHUNK - 1) ? E : e0 + CHUNKB;

    // ---- phase A: per-chunk histogram ----
    for (int k = tid; k < NBK; k += 256) sh[k] = 0;
    __syncthreads();
    for (int e = e0 + tid; e < e1; e += 256) atomicAdd(&sh[edst[e] >> 7], 1);
    __syncthreads();
    for (int k = tid; k < NBK; k += 256) H[k * NCHUNK + c] = sh[k];

    gbar(ctr + 0, NCHUNK);

    // ---- phase B: block b = bucket; exclusive scan H[b][*] over chunks ----
    {
        const int b = blockIdx.x;
        const int base = 4 * tid;
        int v0 = (base + 0 < NCHUNK) ? H[b * NCHUNK + base + 0] : 0;
        int v1 = (base + 1 < NCHUNK) ? H[b * NCHUNK + base + 1] : 0;
        int v2 = (base + 2 < NCHUNK) ? H[b * NCHUNK + base + 2] : 0;
        int v3 = (base + 3 < NCHUNK) ? H[b * NCHUNK + base + 3] : 0;
        const int p1 = v0 + v1, p2 = p1 + v2, tt = p2 + v3;
        int x = tt;
#pragma unroll
        for (int o = 1; o < 64; o <<= 1) { int y = __shfl_up(x, o); if (lane >= o) x += y; }
        __syncthreads();                  // sh reuse (phase A done)
        if (lane == 63) sh[wid] = x;
        __syncthreads();
        int add = 0;
        for (int w = 0; w < wid; ++w) add += sh[w];
        const int excl = add + x - tt;
        if (base + 0 < NCHUNK) H[b * NCHUNK + base + 0] = excl;
        if (base + 1 < NCHUNK) H[b * NCHUNK + base + 1] = excl + v0;
        if (base + 2 < NCHUNK) H[b * NCHUNK + base + 2] = excl + p1;
        if (base + 3 < NCHUNK) H[b * NCHUNK + base + 3] = excl + p2;
        if (tid == 255) bstart[b] = excl + tt;     // bucket total
    }

    gbar(ctr + 1, NCHUNK);

    // ---- phase C: block 0 scans bucket totals ----
    if (blockIdx.x == 0 && tid < 64) {
        int running = 0;
        for (int b = 0; b < NBK; b += 64) {
            const int idx = b + lane;
            const int v = (idx < NBK) ? bstart[idx] : 0;
            int x = v;
#pragma unroll
            for (int o = 1; o < 64; o <<= 1) { int y = __shfl_up(x, o); if (lane >= o) x += y; }
            if (idx < NBK) bstart[idx] = running + x - v;
            running += __shfl(x, 63);
        }
        if (lane == 0) bstart[NBK] = E;
    }

    gbar(ctr + 2, NCHUNK);

    // ---- phase D: scatter packed (dstlow<<24 | src), LDS cursors ----
    for (int k = tid; k < NBK; k += 256) sh[k] = bstart[k] + H[k * NCHUNK + c];
    __syncthreads();
    for (int e = e0 + tid; e < e1; e += 256) {
        const int d = edst[e];
        const int s = esrc[e];
        const int pos = atomicAdd(&sh[d >> 7], 1);
        pairs[pos] = ((unsigned)(d & 127) << 24) | (unsigned)s;
    }
}

// ---------------------------------------------------------------------------
// k_reduce2 v4: 512 threads (8 waves) per bucket; bf16 msg (77MB fetch),
// uint2 gathers (dword-granularity, 4 edges/wave-gather), tail lanes redirect
// to zeroed ZROW (1 cndmask, no mask VALU). shfl_xor merge; fused LN.
// ---------------------------------------------------------------------------
__global__ __launch_bounds__(512) void k_reduce2(const unsigned short* __restrict__ msgb,
                                                 const unsigned* __restrict__ pairs,
                                                 const int* __restrict__ bstart,
                                                 const float* __restrict__ sc,
                                                 const float* __restrict__ bi,
                                                 float* __restrict__ out) {
    __shared__ int srcs[MAXB];      // 16 KB row-sorted src ids
    __shared__ int cnt[BROWS];
    __shared__ int off[BROWS];
    __shared__ int cur[BROWS];

    const int k = blockIdx.x;
    const int tid = threadIdx.x;
    const int lane = tid & 63;
    const int wid = tid >> 6;
    const int s0 = bstart[k];
    const int s1 = bstart[k + 1];

    for (int i = tid; i < BROWS; i += 512) cnt[i] = 0;
    __syncthreads();

    for (int i = s0 + tid; i < s1; i += 512) atomicAdd(&cnt[pairs[i] >> 24], 1);
    __syncthreads();

    if (tid < 64) {
        const int a = cnt[lane];
        const int b = cnt[64 + lane];
        int xa = a, xb = b;
#pragma unroll
        for (int o = 1; o < 64; o <<= 1) {
            int ya = __shfl_up(xa, o); if (lane >= o) xa += ya;
            int yb = __shfl_up(xb, o); if (lane >= o) xb += yb;
        }
        const int tot_a = __shfl(xa, 63);
        off[lane]      = xa - a;
        off[64 + lane] = tot_a + xb - b;
        cur[lane]      = off[lane];
        cur[64 + lane] = off[64 + lane];
    }
    __syncthreads();

    for (int i = s0 + tid; i < s1; i += 512) {
        const unsigned p = pairs[i];
        const int pos = atomicAdd(&cur[p >> 24], 1);
        if (pos < MAXB) srcs[pos] = (int)(p & 0x1FFFFu);
    }
    __syncthreads();

    const int q = lane >> 4;        // quarter-wave: which edge in group of 4
    const int c = lane & 15;        // 4-col group: cols 4c..4c+3

    for (int r = wid; r < BROWS; r += 8) {
        const int dst = k * BROWS + r;
        if (dst >= N_DST) break;
        const int rn = cnt[r];
        const int ro = off[r];

        float ax = 0.f, ay = 0.f, az = 0.f, aw = 0.f;
        for (int b0 = 0; b0 < rn; b0 += 32) {      // 32 edges per iter, 8 gathers
#pragma unroll
            for (int j = 0; j < 8; ++j) {
                if (b0 + 4 * j >= rn) break;          // wave-uniform early out
                const int ei = b0 + 4 * j + q;
                const int sj = (ei < rn) ? srcs[ro + ei] : ZROW;   // 1 cndmask
                const uint2 v = *reinterpret_cast<const uint2*>(
                    msgb + (size_t)sj * D + c * 4);
                ax += asf(v.x << 16);
                ay += asf(v.x & 0xFFFF0000u);
                az += asf(v.y << 16);
                aw += asf(v.y & 0xFFFF0000u);
            }
        }

        // combine the 4 quarter-wave partial sums
        ax += __shfl_xor(ax, 32); ay += __shfl_xor(ay, 32);
        az += __shfl_xor(az, 32); aw += __shfl_xor(aw, 32);
        ax += __shfl_xor(ax, 16); ay += __shfl_xor(ay, 16);
        az += __shfl_xor(az, 16); aw += __shfl_xor(aw, 16);

        // LayerNorm over 64 cols = 16 lanes x 4 comps
        float s = (ax + ay) + (az + aw);
#pragma unroll
        for (int o = 8; o > 0; o >>= 1) s += __shfl_xor(s, o);
        const float mu = s * (1.0f / D);
        const float dx = ax - mu, dy = ay - mu, dz = az - mu, dw = aw - mu;
        float s2 = (dx * dx + dy * dy) + (dz * dz + dw * dw);
#pragma unroll
        for (int o = 8; o > 0; o >>= 1) s2 += __shfl_xor(s2, o);
        const float rs = rsqrtf(s2 * (1.0f / D) + LN_EPS);

        if (lane < 16) {
            const float4 scv = *reinterpret_cast<const float4*>(sc + c * 4);
            const float4 biv = *reinterpret_cast<const float4*>(bi + c * 4);
            float4 o4;
            o4.x = dx * rs * scv.x + biv.x;
            o4.y = dy * rs * scv.y + biv.y;
            o4.z = dz * rs * scv.z + biv.z;
            o4.w = dw * rs * scv.w + biv.w;
            *reinterpret_cast<float4*>(out + (size_t)dst * D + c * 4) = o4;
        }
    }
}

// ---------------------------------------------------------------------------
extern "C" void kernel_launch(void* const* d_in, const int* in_sizes, int n_in,
                              void* d_out, int out_size, void* d_ws, size_t ws_size,
                              hipStream_t stream) {
    const float* feat = (const float*)d_in[0];
    const int*   esrc = (const int*)d_in[1];
    const int*   edst = (const int*)d_in[2];
    const float* Ww   = (const float*)d_in[3];
    const float* Fw   = (const float*)d_in[4];
    const float* sc   = (const float*)d_in[5];
    const float* bi   = (const float*)d_in[6];
    float* out = (float*)d_out;

    char* ws = (char*)d_ws;
    unsigned short* msgb = (unsigned short*)(ws);            // 12.8 MB (100001 rows)
    unsigned* pairs  = (unsigned*)(ws + 26u * 1024 * 1024);  // 6.4 MB
    int*      H      = (int*)(ws + 33u * 1024 * 1024);       // 782*782*4 = 2.45 MB
    int*      bstart = (int*)(ws + 36u * 1024 * 1024);       // 783*4
    int*      ctr    = (int*)(ws + 36u * 1024 * 1024 + 4096);// 3 barrier counters

    // 3 graph nodes total (was 8): film -> fused sort -> reduce
    k_film   <<<782, 256, 0, stream>>>(feat, Ww, Fw, msgb, ctr);
    k_sort   <<<NCHUNK, 256, 0, stream>>>(esrc, edst, H, bstart, pairs, ctr);
    k_reduce2<<<NBK, 512, 0, stream>>>(msgb, pairs, bstart, sc, bi, out);
}